// Round 3
// baseline (407.202 us; speedup 1.0000x reference)
//
#include <hip/hip_runtime.h>
#include <cstdint>
#include <cstddef>

#define NEG_SLOPE 0.2f
#define LOG2E 1.44269504f

typedef __attribute__((ext_vector_type(8))) short short8;   // 8 bf16 (4 VGPRs)
typedef __attribute__((ext_vector_type(4))) float f32x4;    // MFMA accumulator

__device__ __forceinline__ float bf2f(unsigned short u) {
    union { unsigned int i; float f; } x; x.i = ((unsigned int)u) << 16; return x.f;
}
__device__ __forceinline__ unsigned short f2bf(float f) {
    union { float f; unsigned int i; } x;
    x.f = f;
    unsigned int u = x.i;
    return (unsigned short)((u + 0x7FFFu + ((u >> 16) & 1u)) >> 16);   // RNE
}

// 8-lane sum via DPP (VALU pipe, no ds_bpermute): xor1, xor2 quad_perms,
// then row_half_mirror picks up the other quad's sum. Requires the 8-lane
// group to be lane-aligned to 8 and uniformly active (true here).
__device__ __forceinline__ float dpp_sum8(float p) {
    p += __int_as_float(__builtin_amdgcn_update_dpp(0, __float_as_int(p), 0xB1, 0xF, 0xF, true));  // quad_perm [1,0,3,2]
    p += __int_as_float(__builtin_amdgcn_update_dpp(0, __float_as_int(p), 0x4E, 0xF, 0xF, true));  // quad_perm [2,3,0,1]
    p += __int_as_float(__builtin_amdgcn_update_dpp(0, __float_as_int(p), 0x141, 0xF, 0xF, true)); // row_half_mirror
    return p;
}

// =====================================================================
// Weight prep (all 3 layers in one launch) + zero the CSR count array:
// Bt[n][k] = bf16([Wl | Wr][k][n]); layer0/1: dout=128, layer2: dout=32.
// =====================================================================
__global__ __launch_bounds__(256) void prep_w_all(
    const float* __restrict__ Wl0, const float* __restrict__ Wr0,
    const float* __restrict__ Wl1, const float* __restrict__ Wr1,
    const float* __restrict__ Wl2, const float* __restrict__ Wr2,
    unsigned short* __restrict__ Bt0, unsigned short* __restrict__ Bt1,
    unsigned short* __restrict__ Bt2, int* __restrict__ cnt, int N)
{
    int idx = blockIdx.x * 256 + threadIdx.x;
    for (int i = idx; i < N; i += gridDim.x * 256) cnt[i] = 0;
    const int SZ = 256 * 128;     // layer0/1 table elems
    const float *Wl, *Wr; unsigned short* Bt; int dout;
    if (idx < SZ)              { Wl = Wl0; Wr = Wr0; Bt = Bt0; dout = 128; }
    else if (idx < 2 * SZ)     { Wl = Wl1; Wr = Wr1; Bt = Bt1; dout = 128; idx -= SZ; }
    else if (idx < 2 * SZ + 64 * 128) { Wl = Wl2; Wr = Wr2; Bt = Bt2; dout = 32; idx -= 2 * SZ; }
    else return;
    int n = idx >> 7, k = idx & 127;
    float v = (n < dout) ? Wl[(size_t)k * dout + n] : Wr[(size_t)k * dout + (n - dout)];
    Bt[idx] = f2bf(v);
}

// =====================================================================
// MFMA GEMM, LDS-FREE: XL(bf16) | XR(bf16) = A[M x 128] @ Bt^T + b.
// Rationale: A has ZERO cross-wave reuse (each wave owns its 16 rows and
// reuses the A fragment in registers across all NT column tiles), and B
// is a <=64 KB table that is L2-resident (re-read by every row block at
// ~34 TB/s L2 BW). So LDS staging buys nothing: load fragments straight
// from global each k-step. No __syncthreads, LDS 52KB -> 0, occupancy
// 3 blocks/CU -> ~6. Every 64B line is fully consumed.
// Block = 64 rows x BN cols, 256 threads (4 waves).
// =====================================================================
template<int BN, bool ABF16>
__global__ __launch_bounds__(256) void gemm_mfma(
    const void* __restrict__ Avoid, int M,
    const unsigned short* __restrict__ Bt,
    const float* __restrict__ bl, const float* __restrict__ br,
    int dout, unsigned short* __restrict__ XL, unsigned short* __restrict__ XR)
{
    constexpr int NT = BN / 16;
    const int t    = threadIdx.x;
    const int w    = t >> 6;
    const int lane = t & 63;
    const int fr   = lane & 15;
    const int quad = lane >> 4;
    const int m0 = blockIdx.x * 64;
    const int n0 = blockIdx.y * BN;

    const int arow = m0 + w * 16 + fr;                       // A row this lane reads
    // OOB rows: clamp the LOAD address (values are garbage but the epilogue
    // guards every store by row < M, and garbage rows are never stored).
    const size_t abase = (size_t)(arow < M ? arow : 0) * 128 + quad * 8;
    const unsigned short* __restrict__ bq = Bt + (size_t)(n0 + fr) * 128 + quad * 8;

    f32x4 acc[NT] = {};
#pragma unroll
    for (int k0 = 0; k0 < 128; k0 += 32) {
        short8 afr;
        if (ABF16) {
            afr = *(const short8*)((const unsigned short*)Avoid + abase + k0);
        } else {
            const float* Af = (const float*)Avoid;
            float4 lo = *(const float4*)(Af + abase + k0);
            float4 hi = *(const float4*)(Af + abase + k0 + 4);
            afr[0] = (short)f2bf(lo.x); afr[1] = (short)f2bf(lo.y);
            afr[2] = (short)f2bf(lo.z); afr[3] = (short)f2bf(lo.w);
            afr[4] = (short)f2bf(hi.x); afr[5] = (short)f2bf(hi.y);
            afr[6] = (short)f2bf(hi.z); afr[7] = (short)f2bf(hi.w);
        }
#pragma unroll
        for (int j = 0; j < NT; ++j) {
            short8 bfr = *(const short8*)(bq + j * 16 * 128 + k0);
            acc[j] = __builtin_amdgcn_mfma_f32_16x16x32_bf16(afr, bfr, acc[j], 0, 0, 0);
        }
    }

    // ---- epilogue: +bias, bf16 stores into XL | XR
#pragma unroll
    for (int j = 0; j < NT; ++j) {
        int col = n0 + j * 16 + fr;
        float bias = (col < dout) ? bl[col] : br[col - dout];
#pragma unroll
        for (int r = 0; r < 4; ++r) {
            int row = m0 + w * 16 + quad * 4 + r;
            if (row < M) {
                unsigned short o = f2bf(acc[j][r] + bias);
                if (col < dout) XL[(size_t)row * dout + col] = o;
                else            XR[(size_t)row * dout + (col - dout)] = o;
            }
        }
    }
}

// =====================================================================
// CSR build over dst: count+rank -> 3-phase device scan -> place.
// =====================================================================
__global__ void count_rank_kernel(const int* __restrict__ dst, int E,
                                  int* __restrict__ cnt, unsigned short* __restrict__ rank)
{
    int e = blockIdx.x * blockDim.x + threadIdx.x;
    if (e < E) {
        int p = atomicAdd(&cnt[dst[e]], 1);
        rank[e] = (unsigned short)p;
    }
}

__global__ __launch_bounds__(256) void scan_partial(
    const int* __restrict__ cnt, int N, int* __restrict__ bsum)
{
    __shared__ int red[4];
    const int t = threadIdx.x;
    const int base = blockIdx.x * 2048;
    int s = 0;
#pragma unroll
    for (int i = 0; i < 8; ++i) {
        int idx = base + t + i * 256;
        if (idx < N) s += cnt[idx];
    }
#pragma unroll
    for (int off = 32; off >= 1; off >>= 1) s += __shfl_xor(s, off);
    if ((t & 63) == 0) red[t >> 6] = s;
    __syncthreads();
    if (t == 0) bsum[blockIdx.x] = red[0] + red[1] + red[2] + red[3];
}

__global__ __launch_bounds__(256) void scan_bsums(
    int* __restrict__ bsum, int nb, int E, int* __restrict__ rowptr, int N)
{
    __shared__ int sh[256];
    const int t = threadIdx.x;
    int v = (t < nb) ? bsum[t] : 0;
    sh[t] = v;
    __syncthreads();
    for (int off = 1; off < 256; off <<= 1) {
        int u = (t >= off) ? sh[t - off] : 0;
        __syncthreads();
        sh[t] += u;
        __syncthreads();
    }
    if (t < nb) bsum[t] = sh[t] - v;   // exclusive prefix
    if (t == 0) rowptr[N] = E;
}

__global__ __launch_bounds__(256) void scan_final(
    const int* __restrict__ cnt, int N, const int* __restrict__ bsum,
    int* __restrict__ rowptr)
{
    __shared__ int sdat[2048];
    __shared__ int tsum[256];
    const int t = threadIdx.x;
    const int base = blockIdx.x * 2048;
#pragma unroll
    for (int i = 0; i < 8; ++i) {
        int idx = base + t + i * 256;
        sdat[t + i * 256] = (idx < N) ? cnt[idx] : 0;
    }
    __syncthreads();
    int vals[8];
    int s = 0;
#pragma unroll
    for (int j = 0; j < 8; ++j) { vals[j] = sdat[t * 8 + j]; s += vals[j]; }
    tsum[t] = s;
    __syncthreads();
    for (int off = 1; off < 256; off <<= 1) {
        int u = (t >= off) ? tsum[t - off] : 0;
        __syncthreads();
        tsum[t] += u;
        __syncthreads();
    }
    int run = bsum[blockIdx.x] + tsum[t] - s;   // exclusive prefix of this chunk
#pragma unroll
    for (int j = 0; j < 8; ++j) { sdat[t * 8 + j] = run; run += vals[j]; }
    __syncthreads();
#pragma unroll
    for (int i = 0; i < 8; ++i) {
        int idx = base + t + i * 256;
        if (idx < N) rowptr[idx] = sdat[t + i * 256];
    }
}

__global__ void place_kernel(const int* __restrict__ src, const int* __restrict__ dst,
                             const unsigned short* __restrict__ rank, int E,
                             const int* __restrict__ rowptr,
                             unsigned short* __restrict__ csr_src)
{
    int e = blockIdx.x * blockDim.x + threadIdx.x;
    if (e < E)
        csr_src[rowptr[dst[e]] + rank[e]] = (unsigned short)src[e];
}

// =====================================================================
// Fused GATv2 edge phase — bf16 xl/xr tables, bf16 output, 4 ch/lane,
// straight-line scalar float4 math, dpp_sum8 head reduce (VALU pipe),
// leaky folded into the logit dot (leaky(s) = 0.6s + 0.4|s| exactly).
// Measured at the scattered-gather fill-BW ceiling (~2.05 TB/s) — kept
// unchanged this round.
// =====================================================================
template<int H>
__global__ __launch_bounds__(256, 4) void gat_fused(
    const unsigned short* __restrict__ xl, const unsigned short* __restrict__ xr,
    const int* __restrict__ rowptr, const unsigned short* __restrict__ csr_src,
    const float* __restrict__ att, const float* __restrict__ bias,
    unsigned short* __restrict__ hout, int hstride, int N)
{
    constexpr int HC  = 32 * H;
    constexpr int LPE = HC / 4;      // lanes per edge (H=4: 32, H=1: 8)
    constexpr int EPW = 64 / LPE;    // edge slots per wave (2 / 8)
    const int node = blockIdx.x * 4 + (threadIdx.x >> 6);
    if (node >= N) return;
    const int lane = threadIdx.x & 63;
    const int q    = lane % LPE;
    const int slot = lane / LPE;
    const int rs   = rowptr[node];
    const int re   = rowptr[node + 1];

    const unsigned short* __restrict__ xlb = xl + 4 * q;
    float4 xri;
    {
        ushort4 u = *(const ushort4*)(xr + (size_t)node * HC + 4 * q);
        xri.x = bf2f(u.x); xri.y = bf2f(u.y); xri.z = bf2f(u.z); xri.w = bf2f(u.w);
    }
    // logit coefs with leaky folded, exp2 domain
    float4 b1, b2;
    {
        float4 a = *(const float4*)(att + 4 * q);
        const float c1 = 0.5f * (1.0f + NEG_SLOPE) * LOG2E;   // 0.6*log2e
        const float c2 = 0.5f * (1.0f - NEG_SLOPE) * LOG2E;   // 0.4*log2e
        b1.x = a.x * c1; b1.y = a.y * c1; b1.z = a.z * c1; b1.w = a.w * c1;
        b2.x = a.x * c2; b2.y = a.y * c2; b2.z = a.z * c2; b2.w = a.w * c2;
    }

    float l = 0.f;
    float4 acc = make_float4(0.f, 0.f, 0.f, 0.f);

    auto ld4 = [&](int s) -> float4 {
        ushort4 u = *(const ushort4*)(xlb + (size_t)s * HC);
        float4 v;
        v.x = bf2f(u.x); v.y = bf2f(u.y); v.z = bf2f(u.z); v.w = bf2f(u.w);
        return v;
    };

    auto edge_w = [&](const float4& v) -> float {   // exp2(att . leakyrelu(v+xri))
        float sx = v.x + xri.x, sy = v.y + xri.y, sz = v.z + xri.z, sw = v.w + xri.w;
        float p  = b1.x * sx;
        float pq = b2.x * fabsf(sx);
        p  = fmaf(b1.y, sy, p);
        pq = fmaf(b2.y, fabsf(sy), pq);
        p  = fmaf(b1.z, sz, p);
        pq = fmaf(b2.z, fabsf(sz), pq);
        p  = fmaf(b1.w, sw, p);
        pq = fmaf(b2.w, fabsf(sw), pq);
        p += pq;
        p = dpp_sum8(p);                 // 8-lane head reduce, VALU pipe
        return exp2f(p);
    };

    // ---- self-loop (src = dst = node), slot 0 only
    if (slot == 0) {
        float4 v = ld4(node);
        float w = edge_w(v);
        l = w;
        acc.x = w * v.x; acc.y = w * v.y; acc.z = w * v.z; acc.w = w * v.w;
    }

    // ---- incoming edges, strided per slot, unrolled x2 (no predication)
    int k = rs + slot;
    for (; k + EPW < re; k += 2 * EPW) {
        int s0 = csr_src[k];
        int s1 = csr_src[k + EPW];
        float4 v0 = ld4(s0);
        float4 v1 = ld4(s1);
        float w0 = edge_w(v0);
        float w1 = edge_w(v1);
        l += w0 + w1;
        acc.x = fmaf(w0, v0.x, fmaf(w1, v1.x, acc.x));
        acc.y = fmaf(w0, v0.y, fmaf(w1, v1.y, acc.y));
        acc.z = fmaf(w0, v0.z, fmaf(w1, v1.z, acc.z));
        acc.w = fmaf(w0, v0.w, fmaf(w1, v1.w, acc.w));
    }
    if (k < re) {
        int s0 = csr_src[k];
        float4 v0 = ld4(s0);
        float w0 = edge_w(v0);
        l += w0;
        acc.x = fmaf(w0, v0.x, acc.x);
        acc.y = fmaf(w0, v0.y, acc.y);
        acc.z = fmaf(w0, v0.z, acc.z);
        acc.w = fmaf(w0, v0.w, acc.w);
    }

    // ---- merge edge slots: plain sums (once per node)
#pragma unroll
    for (int mask = LPE; mask < 64; mask <<= 1) {
        l     += __shfl_xor(l, mask);
        acc.x += __shfl_xor(acc.x, mask);
        acc.y += __shfl_xor(acc.y, mask);
        acc.z += __shfl_xor(acc.z, mask);
        acc.w += __shfl_xor(acc.w, mask);
    }

    if (lane < LPE) {
        const float4 bi = *(const float4*)(bias + 4 * q);
        float inv = 1.f / (l + 1e-16f);
        float4 o;
        o.x = acc.x * inv + bi.x;
        o.y = acc.y * inv + bi.y;
        o.z = acc.z * inv + bi.z;
        o.w = acc.w * inv + bi.w;
        o.x = (o.x > 0.f) ? o.x : expm1f(o.x);
        o.y = (o.y > 0.f) ? o.y : expm1f(o.y);
        o.z = (o.z > 0.f) ? o.z : expm1f(o.z);
        o.w = (o.w > 0.f) ? o.w : expm1f(o.w);
        ushort4 ob;
        ob.x = f2bf(o.x); ob.y = f2bf(o.y); ob.z = f2bf(o.z); ob.w = f2bf(o.w);
        *(ushort4*)(hout + (size_t)node * hstride + 4 * q) = ob;
    }
}

// =====================================================================
// Fused mean-pool + MLP head (h is bf16). One block per graph; batch is
// SORTED so graph b's nodes are rows [lower_bound(b), lower_bound(b+1)).
// =====================================================================
__global__ __launch_bounds__(128) void pool_head_kernel(
    const unsigned short* __restrict__ h, int hstride,
    const int* __restrict__ batch, int N,
    const float* __restrict__ meta,
    const float* __restrict__ Wh1, const float* __restrict__ bh1,
    const float* __restrict__ Wh2, const float* __restrict__ bh2,
    float* __restrict__ out)
{
    const int b = blockIdx.x;
    const int t = threadIdx.x;
    __shared__ float s[128];
    __shared__ float z[44];

    int lo = 0, hi = N;
    while (lo < hi) { int mid = (lo + hi) >> 1; if (batch[mid] < b) lo = mid + 1; else hi = mid; }
    int lo2 = lo, hi2 = N;
    while (lo2 < hi2) { int mid = (lo2 + hi2) >> 1; if (batch[mid] < b + 1) lo2 = mid + 1; else hi2 = mid; }
    const int start = lo, end = lo2;

    const int c = t & 31, r = t >> 5;     // 4 rows x 32 channels in flight
    float acc = 0.f;
    for (int row = start + r; row < end; row += 4)
        acc += bf2f(h[(size_t)row * hstride + c]);
    s[t] = acc;
    __syncthreads();
    if (t < 32) {
        float sum = s[t] + s[t + 32] + s[t + 64] + s[t + 96];
        z[t] = sum / fmaxf((float)(end - start), 1.0f);
    } else if (t < 44) {
        z[t] = meta[(size_t)b * 12 + (t - 32)];
    }
    __syncthreads();
    if (t < 32) {
        float hj = bh1[t];
#pragma unroll
        for (int k = 0; k < 44; ++k)
            hj = fmaf(z[k], Wh1[k * 32 + t], hj);
        hj = fmaxf(hj, 0.f);
        float p = hj * Wh2[t];
#pragma unroll
        for (int off = 16; off >= 1; off >>= 1)
            p += __shfl_xor(p, off, 32);
        if (t == 0) out[b] = p + bh2[0];
    }
}

// =====================================================================
extern "C" void kernel_launch(void* const* d_in, const int* in_sizes, int n_in,
                              void* d_out, int out_size, void* d_ws, size_t ws_size,
                              hipStream_t stream)
{
    const float* x     = (const float*)d_in[0];
    const int*   ei    = (const int*)d_in[1];
    const int*   batch = (const int*)d_in[2];
    const float* meta  = (const float*)d_in[3];
    const float* Wl[3]  = {(const float*)d_in[4],  (const float*)d_in[10], (const float*)d_in[16]};
    const float* bl[3]  = {(const float*)d_in[5],  (const float*)d_in[11], (const float*)d_in[17]};
    const float* Wr[3]  = {(const float*)d_in[6],  (const float*)d_in[12], (const float*)d_in[18]};
    const float* br[3]  = {(const float*)d_in[7],  (const float*)d_in[13], (const float*)d_in[19]};
    const float* att[3] = {(const float*)d_in[8],  (const float*)d_in[14], (const float*)d_in[20]};
    const float* bb[3]  = {(const float*)d_in[9],  (const float*)d_in[15], (const float*)d_in[21]};
    const float* Wh1 = (const float*)d_in[22];
    const float* bh1 = (const float*)d_in[23];
    const float* Wh2 = (const float*)d_in[24];
    const float* bh2 = (const float*)d_in[25];
    float* out = (float*)d_out;

    const int N  = in_sizes[0] / 128;
    const int E  = in_sizes[1] / 2;
    const int B  = in_sizes[3] / 12;
    const int NB = (N + 2047) / 2048;   // scan tiles (<= 256)

    char* wsp = (char*)d_ws;
    size_t off_ = 0;
    auto alloc = [&](size_t bytes) {
        char* p = wsp + off_;
        off_ = (off_ + bytes + 255) & ~(size_t)255;
        return p;
    };
    unsigned short* xlbuf = (unsigned short*)alloc((size_t)N * 128 * 2);  // bf16 gather table
    unsigned short* xrbuf = (unsigned short*)alloc((size_t)N * 128 * 2);  // bf16 xr table
    unsigned short* hbuf  = (unsigned short*)alloc((size_t)N * 128 * 2);  // bf16 layer output
    int*   cnt     = (int*)alloc((size_t)N * 4);
    int*   rowptr  = (int*)alloc((size_t)(N + 1) * 4);
    unsigned short* rank    = (unsigned short*)alloc((size_t)E * 2);  // rank within dst bucket
    unsigned short* csr_src = (unsigned short*)alloc((size_t)E * 2);  // src < 65536
    unsigned short* Bt0     = (unsigned short*)alloc((size_t)256 * 128 * 2);
    unsigned short* Bt1     = (unsigned short*)alloc((size_t)256 * 128 * 2);
    unsigned short* Bt2     = (unsigned short*)alloc((size_t)64 * 128 * 2);
    int*   bsum    = (int*)alloc((size_t)256 * 4);

    const int* srcI = ei;
    const int* dstI = ei + E;

    // ---- weight prep + cnt zeroing (one launch, no memset dispatch)
    prep_w_all<<<(2 * 256 * 128 + 64 * 128 + 255) / 256, 256, 0, stream>>>(
        Wl[0], Wr[0], Wl[1], Wr[1], Wl[2], Wr[2], Bt0, Bt1, Bt2, cnt, N);

    // ---- CSR over dst (real edges; self-loops handled inside gat_fused)
    count_rank_kernel<<<(E + 255) / 256, 256, 0, stream>>>(dstI, E, cnt, rank);
    scan_partial<<<NB, 256, 0, stream>>>(cnt, N, bsum);
    scan_bsums<<<1, 256, 0, stream>>>(bsum, NB, E, rowptr, N);
    scan_final<<<NB, 256, 0, stream>>>(cnt, N, bsum, rowptr);
    place_kernel<<<(E + 255) / 256, 256, 0, stream>>>(srcI, dstI, rank, E, rowptr, csr_src);

    const int GB = (N + 3) / 4;     // gat_fused blocks (4 nodes / 256-thread block)
    const int MB = (N + 63) / 64;   // gemm row-tiles (BM=64)

    // ---- layer 0 (din=128 f32, H=4, C=32, concat)
    {
        gemm_mfma<128, false><<<dim3(MB, 2), 256, 0, stream>>>(x, N, Bt0, bl[0], br[0], 128, xlbuf, xrbuf);
        gat_fused<4><<<GB, 256, 0, stream>>>(xlbuf, xrbuf, rowptr, csr_src, att[0], bb[0], hbuf, 128, N);
    }
    // ---- layer 1 (din=128 bf16)
    {
        gemm_mfma<128, true><<<dim3(MB, 2), 256, 0, stream>>>(hbuf, N, Bt1, bl[1], br[1], 128, xlbuf, xrbuf);
        gat_fused<4><<<GB, 256, 0, stream>>>(xlbuf, xrbuf, rowptr, csr_src, att[1], bb[1], hbuf, 128, N);
    }
    // ---- layer 2 (H=1, concat=False -> mean over 1 head = identity)
    {
        gemm_mfma<64, true><<<dim3(MB, 1), 256, 0, stream>>>(hbuf, N, Bt2, bl[2], br[2], 32, xlbuf, xrbuf);
        gat_fused<1><<<GB, 256, 0, stream>>>(xlbuf, xrbuf, rowptr, csr_src, att[2], bb[2], hbuf, 32, N);
    }
    // ---- fused global mean pool + head (batch sorted -> binary search, no atomics)
    pool_head_kernel<<<B, 128, 0, stream>>>(hbuf, 32, batch, N, meta, Wh1, bh1, Wh2, bh2, out);
}

// Round 4
// 361.026 us; speedup vs baseline: 1.1279x; 1.1279x over previous
//
#include <hip/hip_runtime.h>
#include <cstdint>
#include <cstddef>

#define NEG_SLOPE 0.2f
#define LOG2E 1.44269504f

typedef __attribute__((ext_vector_type(8))) short short8;   // 8 bf16 (4 VGPRs)
typedef __attribute__((ext_vector_type(4))) float f32x4;    // MFMA accumulator

__device__ __forceinline__ float bf2f(unsigned short u) {
    union { unsigned int i; float f; } x; x.i = ((unsigned int)u) << 16; return x.f;
}
__device__ __forceinline__ unsigned short f2bf(float f) {
    union { float f; unsigned int i; } x;
    x.f = f;
    unsigned int u = x.i;
    return (unsigned short)((u + 0x7FFFu + ((u >> 16) & 1u)) >> 16);   // RNE
}

// 8-lane sum via DPP (VALU pipe, no ds_bpermute): xor1, xor2 quad_perms,
// then row_half_mirror picks up the other quad's sum. Requires the 8-lane
// group to be lane-aligned to 8 and uniformly active (true here).
__device__ __forceinline__ float dpp_sum8(float p) {
    p += __int_as_float(__builtin_amdgcn_update_dpp(0, __float_as_int(p), 0xB1, 0xF, 0xF, true));  // quad_perm [1,0,3,2]
    p += __int_as_float(__builtin_amdgcn_update_dpp(0, __float_as_int(p), 0x4E, 0xF, 0xF, true));  // quad_perm [2,3,0,1]
    p += __int_as_float(__builtin_amdgcn_update_dpp(0, __float_as_int(p), 0x141, 0xF, 0xF, true)); // row_half_mirror
    return p;
}

// =====================================================================
// Weight prep (all 3 layers in one launch) + zero the CSR count array:
// Bt[n][k] = bf16([Wl | Wr][k][n]); layer0/1: dout=128, layer2: dout=32.
// =====================================================================
__global__ __launch_bounds__(256) void prep_w_all(
    const float* __restrict__ Wl0, const float* __restrict__ Wr0,
    const float* __restrict__ Wl1, const float* __restrict__ Wr1,
    const float* __restrict__ Wl2, const float* __restrict__ Wr2,
    unsigned short* __restrict__ Bt0, unsigned short* __restrict__ Bt1,
    unsigned short* __restrict__ Bt2, int* __restrict__ cnt, int N)
{
    int idx = blockIdx.x * 256 + threadIdx.x;
    for (int i = idx; i < N; i += gridDim.x * 256) cnt[i] = 0;
    const int SZ = 256 * 128;     // layer0/1 table elems
    const float *Wl, *Wr; unsigned short* Bt; int dout;
    if (idx < SZ)              { Wl = Wl0; Wr = Wr0; Bt = Bt0; dout = 128; }
    else if (idx < 2 * SZ)     { Wl = Wl1; Wr = Wr1; Bt = Bt1; dout = 128; idx -= SZ; }
    else if (idx < 2 * SZ + 64 * 128) { Wl = Wl2; Wr = Wr2; Bt = Bt2; dout = 32; idx -= 2 * SZ; }
    else return;
    int n = idx >> 7, k = idx & 127;
    float v = (n < dout) ? Wl[(size_t)k * dout + n] : Wr[(size_t)k * dout + (n - dout)];
    Bt[idx] = f2bf(v);
}

// =====================================================================
// MFMA GEMM, B-in-LDS / A-direct: XL | XR = A[M x 128] @ Bt^T + b.
// r2 (A+B in LDS, 52KB, 3 blk/CU) = fast; r3 (no LDS at all) = -30us
// regression from repeated per-lane global B loads on the MFMA critical
// path. This keeps B staged in LDS (one copy, ds_read_b128 reuse) and
// drops ONLY the A staging: A has zero cross-wave reuse (each wave's A
// fragment is register-resident across all NT column tiles), so each
// lane loads its 4x16B A fragments straight from global (every 64B line
// fully consumed by 4 lanes), hoisted before the k-loop, overlapping
// the B-staging barrier. LDS 52->35KB => 4 blocks/CU (16 waves/CU).
// Block = 64 rows x BN cols, 256 threads (4 waves).
// =====================================================================
template<int BN, bool ABF16>
__global__ __launch_bounds__(256) void gemm_mfma(
    const void* __restrict__ Avoid, int M,
    const unsigned short* __restrict__ Bt,
    const float* __restrict__ bl, const float* __restrict__ br,
    int dout, unsigned short* __restrict__ XL, unsigned short* __restrict__ XR)
{
    constexpr int LDA = 136;                       // shorts; pad 128+8
    constexpr int NT  = BN / 16;
    __shared__ __attribute__((aligned(16))) unsigned short Bs[BN * LDA];
    const int t  = threadIdx.x;
    const int m0 = blockIdx.x * 64;
    const int n0 = blockIdx.y * BN;

    const int w    = t >> 6;
    const int lane = t & 63;
    const int fr   = lane & 15;
    const int quad = lane >> 4;

    // ---- stage B (BN x 128 bf16 -> LDS), coalesced
#pragma unroll
    for (int i = 0; i < BN / 16; ++i) {
        int c  = t + i * 256;              // short8 chunks
        int n  = c >> 4;                   // 16 chunks per row
        int kc = (c & 15) * 8;
        *(short8*)(Bs + n * LDA + kc) =
            *(const short8*)(Bt + (size_t)(n0 + n) * 128 + kc);
    }

    // ---- load A fragments direct from global (overlaps B staging)
    const int arow = m0 + w * 16 + fr;     // this lane's A row
    // OOB rows: clamp the LOAD address (values are garbage; the epilogue
    // guards every store by row < M so garbage rows are never stored).
    const size_t abase = (size_t)(arow < M ? arow : 0) * 128 + quad * 8;
    short8 afr[4];
    if (ABF16) {
        const unsigned short* A = (const unsigned short*)Avoid;
#pragma unroll
        for (int kk = 0; kk < 4; ++kk)
            afr[kk] = *(const short8*)(A + abase + kk * 32);
    } else {
        const float* A = (const float*)Avoid;
#pragma unroll
        for (int kk = 0; kk < 4; ++kk) {
            float4 lo = *(const float4*)(A + abase + kk * 32);
            float4 hi = *(const float4*)(A + abase + kk * 32 + 4);
            afr[kk][0] = (short)f2bf(lo.x); afr[kk][1] = (short)f2bf(lo.y);
            afr[kk][2] = (short)f2bf(lo.z); afr[kk][3] = (short)f2bf(lo.w);
            afr[kk][4] = (short)f2bf(hi.x); afr[kk][5] = (short)f2bf(hi.y);
            afr[kk][6] = (short)f2bf(hi.z); afr[kk][7] = (short)f2bf(hi.w);
        }
    }
    __syncthreads();

    f32x4 acc[NT] = {};
    const unsigned short* bp = Bs + fr * LDA + quad * 8;
#pragma unroll
    for (int kk = 0; kk < 4; ++kk) {
#pragma unroll
        for (int j = 0; j < NT; ++j) {
            short8 bfr = *(const short8*)(bp + j * 16 * LDA + kk * 32);
            acc[j] = __builtin_amdgcn_mfma_f32_16x16x32_bf16(afr[kk], bfr, acc[j], 0, 0, 0);
        }
    }

    // ---- epilogue: +bias, bf16 stores into XL | XR
#pragma unroll
    for (int j = 0; j < NT; ++j) {
        int col = n0 + j * 16 + fr;
        float bias = (col < dout) ? bl[col] : br[col - dout];
#pragma unroll
        for (int r = 0; r < 4; ++r) {
            int row = m0 + w * 16 + quad * 4 + r;
            if (row < M) {
                unsigned short o = f2bf(acc[j][r] + bias);
                if (col < dout) XL[(size_t)row * dout + col] = o;
                else            XR[(size_t)row * dout + (col - dout)] = o;
            }
        }
    }
}

// =====================================================================
// CSR build over dst: count+rank -> 3-phase device scan -> place.
// =====================================================================
__global__ void count_rank_kernel(const int* __restrict__ dst, int E,
                                  int* __restrict__ cnt, unsigned short* __restrict__ rank)
{
    int e = blockIdx.x * blockDim.x + threadIdx.x;
    if (e < E) {
        int p = atomicAdd(&cnt[dst[e]], 1);
        rank[e] = (unsigned short)p;
    }
}

__global__ __launch_bounds__(256) void scan_partial(
    const int* __restrict__ cnt, int N, int* __restrict__ bsum)
{
    __shared__ int red[4];
    const int t = threadIdx.x;
    const int base = blockIdx.x * 2048;
    int s = 0;
#pragma unroll
    for (int i = 0; i < 8; ++i) {
        int idx = base + t + i * 256;
        if (idx < N) s += cnt[idx];
    }
#pragma unroll
    for (int off = 32; off >= 1; off >>= 1) s += __shfl_xor(s, off);
    if ((t & 63) == 0) red[t >> 6] = s;
    __syncthreads();
    if (t == 0) bsum[blockIdx.x] = red[0] + red[1] + red[2] + red[3];
}

__global__ __launch_bounds__(256) void scan_bsums(
    int* __restrict__ bsum, int nb, int E, int* __restrict__ rowptr, int N)
{
    __shared__ int sh[256];
    const int t = threadIdx.x;
    int v = (t < nb) ? bsum[t] : 0;
    sh[t] = v;
    __syncthreads();
    for (int off = 1; off < 256; off <<= 1) {
        int u = (t >= off) ? sh[t - off] : 0;
        __syncthreads();
        sh[t] += u;
        __syncthreads();
    }
    if (t < nb) bsum[t] = sh[t] - v;   // exclusive prefix
    if (t == 0) rowptr[N] = E;
}

__global__ __launch_bounds__(256) void scan_final(
    const int* __restrict__ cnt, int N, const int* __restrict__ bsum,
    int* __restrict__ rowptr)
{
    __shared__ int sdat[2048];
    __shared__ int tsum[256];
    const int t = threadIdx.x;
    const int base = blockIdx.x * 2048;
#pragma unroll
    for (int i = 0; i < 8; ++i) {
        int idx = base + t + i * 256;
        sdat[t + i * 256] = (idx < N) ? cnt[idx] : 0;
    }
    __syncthreads();
    int vals[8];
    int s = 0;
#pragma unroll
    for (int j = 0; j < 8; ++j) { vals[j] = sdat[t * 8 + j]; s += vals[j]; }
    tsum[t] = s;
    __syncthreads();
    for (int off = 1; off < 256; off <<= 1) {
        int u = (t >= off) ? tsum[t - off] : 0;
        __syncthreads();
        tsum[t] += u;
        __syncthreads();
    }
    int run = bsum[blockIdx.x] + tsum[t] - s;   // exclusive prefix of this chunk
#pragma unroll
    for (int j = 0; j < 8; ++j) { sdat[t * 8 + j] = run; run += vals[j]; }
    __syncthreads();
#pragma unroll
    for (int i = 0; i < 8; ++i) {
        int idx = base + t + i * 256;
        if (idx < N) rowptr[idx] = sdat[t + i * 256];
    }
}

__global__ void place_kernel(const int* __restrict__ src, const int* __restrict__ dst,
                             const unsigned short* __restrict__ rank, int E,
                             const int* __restrict__ rowptr,
                             unsigned short* __restrict__ csr_src)
{
    int e = blockIdx.x * blockDim.x + threadIdx.x;
    if (e < E)
        csr_src[rowptr[dst[e]] + rank[e]] = (unsigned short)src[e];
}

// =====================================================================
// Fused GATv2 edge phase — bf16 xl/xr tables, bf16 output, 4 ch/lane,
// straight-line scalar float4 math, dpp_sum8 head reduce (VALU pipe),
// leaky folded into the logit dot (leaky(s) = 0.6s + 0.4|s| exactly).
// Measured at the scattered-gather fill ceiling (~2.03 TB/s, FETCH =
// per-XCD-compulsory table fill) across 3 rounds — kept frozen.
// =====================================================================
template<int H>
__global__ __launch_bounds__(256, 4) void gat_fused(
    const unsigned short* __restrict__ xl, const unsigned short* __restrict__ xr,
    const int* __restrict__ rowptr, const unsigned short* __restrict__ csr_src,
    const float* __restrict__ att, const float* __restrict__ bias,
    unsigned short* __restrict__ hout, int hstride, int N)
{
    constexpr int HC  = 32 * H;
    constexpr int LPE = HC / 4;      // lanes per edge (H=4: 32, H=1: 8)
    constexpr int EPW = 64 / LPE;    // edge slots per wave (2 / 8)
    const int node = blockIdx.x * 4 + (threadIdx.x >> 6);
    if (node >= N) return;
    const int lane = threadIdx.x & 63;
    const int q    = lane % LPE;
    const int slot = lane / LPE;
    const int rs   = rowptr[node];
    const int re   = rowptr[node + 1];

    const unsigned short* __restrict__ xlb = xl + 4 * q;
    float4 xri;
    {
        ushort4 u = *(const ushort4*)(xr + (size_t)node * HC + 4 * q);
        xri.x = bf2f(u.x); xri.y = bf2f(u.y); xri.z = bf2f(u.z); xri.w = bf2f(u.w);
    }
    // logit coefs with leaky folded, exp2 domain
    float4 b1, b2;
    {
        float4 a = *(const float4*)(att + 4 * q);
        const float c1 = 0.5f * (1.0f + NEG_SLOPE) * LOG2E;   // 0.6*log2e
        const float c2 = 0.5f * (1.0f - NEG_SLOPE) * LOG2E;   // 0.4*log2e
        b1.x = a.x * c1; b1.y = a.y * c1; b1.z = a.z * c1; b1.w = a.w * c1;
        b2.x = a.x * c2; b2.y = a.y * c2; b2.z = a.z * c2; b2.w = a.w * c2;
    }

    float l = 0.f;
    float4 acc = make_float4(0.f, 0.f, 0.f, 0.f);

    auto ld4 = [&](int s) -> float4 {
        ushort4 u = *(const ushort4*)(xlb + (size_t)s * HC);
        float4 v;
        v.x = bf2f(u.x); v.y = bf2f(u.y); v.z = bf2f(u.z); v.w = bf2f(u.w);
        return v;
    };

    auto edge_w = [&](const float4& v) -> float {   // exp2(att . leakyrelu(v+xri))
        float sx = v.x + xri.x, sy = v.y + xri.y, sz = v.z + xri.z, sw = v.w + xri.w;
        float p  = b1.x * sx;
        float pq = b2.x * fabsf(sx);
        p  = fmaf(b1.y, sy, p);
        pq = fmaf(b2.y, fabsf(sy), pq);
        p  = fmaf(b1.z, sz, p);
        pq = fmaf(b2.z, fabsf(sz), pq);
        p  = fmaf(b1.w, sw, p);
        pq = fmaf(b2.w, fabsf(sw), pq);
        p += pq;
        p = dpp_sum8(p);                 // 8-lane head reduce, VALU pipe
        return exp2f(p);
    };

    // ---- self-loop (src = dst = node), slot 0 only
    if (slot == 0) {
        float4 v = ld4(node);
        float w = edge_w(v);
        l = w;
        acc.x = w * v.x; acc.y = w * v.y; acc.z = w * v.z; acc.w = w * v.w;
    }

    // ---- incoming edges, strided per slot, unrolled x2 (no predication)
    int k = rs + slot;
    for (; k + EPW < re; k += 2 * EPW) {
        int s0 = csr_src[k];
        int s1 = csr_src[k + EPW];
        float4 v0 = ld4(s0);
        float4 v1 = ld4(s1);
        float w0 = edge_w(v0);
        float w1 = edge_w(v1);
        l += w0 + w1;
        acc.x = fmaf(w0, v0.x, fmaf(w1, v1.x, acc.x));
        acc.y = fmaf(w0, v0.y, fmaf(w1, v1.y, acc.y));
        acc.z = fmaf(w0, v0.z, fmaf(w1, v1.z, acc.z));
        acc.w = fmaf(w0, v0.w, fmaf(w1, v1.w, acc.w));
    }
    if (k < re) {
        int s0 = csr_src[k];
        float4 v0 = ld4(s0);
        float w0 = edge_w(v0);
        l += w0;
        acc.x = fmaf(w0, v0.x, acc.x);
        acc.y = fmaf(w0, v0.y, acc.y);
        acc.z = fmaf(w0, v0.z, acc.z);
        acc.w = fmaf(w0, v0.w, acc.w);
    }

    // ---- merge edge slots: plain sums (once per node)
#pragma unroll
    for (int mask = LPE; mask < 64; mask <<= 1) {
        l     += __shfl_xor(l, mask);
        acc.x += __shfl_xor(acc.x, mask);
        acc.y += __shfl_xor(acc.y, mask);
        acc.z += __shfl_xor(acc.z, mask);
        acc.w += __shfl_xor(acc.w, mask);
    }

    if (lane < LPE) {
        const float4 bi = *(const float4*)(bias + 4 * q);
        float inv = 1.f / (l + 1e-16f);
        float4 o;
        o.x = acc.x * inv + bi.x;
        o.y = acc.y * inv + bi.y;
        o.z = acc.z * inv + bi.z;
        o.w = acc.w * inv + bi.w;
        o.x = (o.x > 0.f) ? o.x : expm1f(o.x);
        o.y = (o.y > 0.f) ? o.y : expm1f(o.y);
        o.z = (o.z > 0.f) ? o.z : expm1f(o.z);
        o.w = (o.w > 0.f) ? o.w : expm1f(o.w);
        ushort4 ob;
        ob.x = f2bf(o.x); ob.y = f2bf(o.y); ob.z = f2bf(o.z); ob.w = f2bf(o.w);
        *(ushort4*)(hout + (size_t)node * hstride + 4 * q) = ob;
    }
}

// =====================================================================
// Fused mean-pool + MLP head (h is bf16). One block per graph; batch is
// SORTED so graph b's nodes are rows [lower_bound(b), lower_bound(b+1)).
// =====================================================================
__global__ __launch_bounds__(128) void pool_head_kernel(
    const unsigned short* __restrict__ h, int hstride,
    const int* __restrict__ batch, int N,
    const float* __restrict__ meta,
    const float* __restrict__ Wh1, const float* __restrict__ bh1,
    const float* __restrict__ Wh2, const float* __restrict__ bh2,
    float* __restrict__ out)
{
    const int b = blockIdx.x;
    const int t = threadIdx.x;
    __shared__ float s[128];
    __shared__ float z[44];

    int lo = 0, hi = N;
    while (lo < hi) { int mid = (lo + hi) >> 1; if (batch[mid] < b) lo = mid + 1; else hi = mid; }
    int lo2 = lo, hi2 = N;
    while (lo2 < hi2) { int mid = (lo2 + hi2) >> 1; if (batch[mid] < b + 1) lo2 = mid + 1; else hi2 = mid; }
    const int start = lo, end = lo2;

    const int c = t & 31, r = t >> 5;     // 4 rows x 32 channels in flight
    float acc = 0.f;
    for (int row = start + r; row < end; row += 4)
        acc += bf2f(h[(size_t)row * hstride + c]);
    s[t] = acc;
    __syncthreads();
    if (t < 32) {
        float sum = s[t] + s[t + 32] + s[t + 64] + s[t + 96];
        z[t] = sum / fmaxf((float)(end - start), 1.0f);
    } else if (t < 44) {
        z[t] = meta[(size_t)b * 12 + (t - 32)];
    }
    __syncthreads();
    if (t < 32) {
        float hj = bh1[t];
#pragma unroll
        for (int k = 0; k < 44; ++k)
            hj = fmaf(z[k], Wh1[k * 32 + t], hj);
        hj = fmaxf(hj, 0.f);
        float p = hj * Wh2[t];
#pragma unroll
        for (int off = 16; off >= 1; off >>= 1)
            p += __shfl_xor(p, off, 32);
        if (t == 0) out[b] = p + bh2[0];
    }
}

// =====================================================================
extern "C" void kernel_launch(void* const* d_in, const int* in_sizes, int n_in,
                              void* d_out, int out_size, void* d_ws, size_t ws_size,
                              hipStream_t stream)
{
    const float* x     = (const float*)d_in[0];
    const int*   ei    = (const int*)d_in[1];
    const int*   batch = (const int*)d_in[2];
    const float* meta  = (const float*)d_in[3];
    const float* Wl[3]  = {(const float*)d_in[4],  (const float*)d_in[10], (const float*)d_in[16]};
    const float* bl[3]  = {(const float*)d_in[5],  (const float*)d_in[11], (const float*)d_in[17]};
    const float* Wr[3]  = {(const float*)d_in[6],  (const float*)d_in[12], (const float*)d_in[18]};
    const float* br[3]  = {(const float*)d_in[7],  (const float*)d_in[13], (const float*)d_in[19]};
    const float* att[3] = {(const float*)d_in[8],  (const float*)d_in[14], (const float*)d_in[20]};
    const float* bb[3]  = {(const float*)d_in[9],  (const float*)d_in[15], (const float*)d_in[21]};
    const float* Wh1 = (const float*)d_in[22];
    const float* bh1 = (const float*)d_in[23];
    const float* Wh2 = (const float*)d_in[24];
    const float* bh2 = (const float*)d_in[25];
    float* out = (float*)d_out;

    const int N  = in_sizes[0] / 128;
    const int E  = in_sizes[1] / 2;
    const int B  = in_sizes[3] / 12;
    const int NB = (N + 2047) / 2048;   // scan tiles (<= 256)

    char* wsp = (char*)d_ws;
    size_t off_ = 0;
    auto alloc = [&](size_t bytes) {
        char* p = wsp + off_;
        off_ = (off_ + bytes + 255) & ~(size_t)255;
        return p;
    };
    unsigned short* xlbuf = (unsigned short*)alloc((size_t)N * 128 * 2);  // bf16 gather table
    unsigned short* xrbuf = (unsigned short*)alloc((size_t)N * 128 * 2);  // bf16 xr table
    unsigned short* hbuf  = (unsigned short*)alloc((size_t)N * 128 * 2);  // bf16 layer output
    int*   cnt     = (int*)alloc((size_t)N * 4);
    int*   rowptr  = (int*)alloc((size_t)(N + 1) * 4);
    unsigned short* rank    = (unsigned short*)alloc((size_t)E * 2);  // rank within dst bucket
    unsigned short* csr_src = (unsigned short*)alloc((size_t)E * 2);  // src < 65536
    unsigned short* Bt0     = (unsigned short*)alloc((size_t)256 * 128 * 2);
    unsigned short* Bt1     = (unsigned short*)alloc((size_t)256 * 128 * 2);
    unsigned short* Bt2     = (unsigned short*)alloc((size_t)64 * 128 * 2);
    int*   bsum    = (int*)alloc((size_t)256 * 4);

    const int* srcI = ei;
    const int* dstI = ei + E;

    // ---- weight prep + cnt zeroing (one launch, no memset dispatch)
    prep_w_all<<<(2 * 256 * 128 + 64 * 128 + 255) / 256, 256, 0, stream>>>(
        Wl[0], Wr[0], Wl[1], Wr[1], Wl[2], Wr[2], Bt0, Bt1, Bt2, cnt, N);

    // ---- CSR over dst (real edges; self-loops handled inside gat_fused)
    count_rank_kernel<<<(E + 255) / 256, 256, 0, stream>>>(dstI, E, cnt, rank);
    scan_partial<<<NB, 256, 0, stream>>>(cnt, N, bsum);
    scan_bsums<<<1, 256, 0, stream>>>(bsum, NB, E, rowptr, N);
    scan_final<<<NB, 256, 0, stream>>>(cnt, N, bsum, rowptr);
    place_kernel<<<(E + 255) / 256, 256, 0, stream>>>(srcI, dstI, rank, E, rowptr, csr_src);

    const int GB = (N + 3) / 4;     // gat_fused blocks (4 nodes / 256-thread block)
    const int MB = (N + 63) / 64;   // gemm row-tiles (BM=64)

    // ---- layer 0 (din=128 f32, H=4, C=32, concat)
    {
        gemm_mfma<128, false><<<dim3(MB, 2), 256, 0, stream>>>(x, N, Bt0, bl[0], br[0], 128, xlbuf, xrbuf);
        gat_fused<4><<<GB, 256, 0, stream>>>(xlbuf, xrbuf, rowptr, csr_src, att[0], bb[0], hbuf, 128, N);
    }
    // ---- layer 1 (din=128 bf16)
    {
        gemm_mfma<128, true><<<dim3(MB, 2), 256, 0, stream>>>(hbuf, N, Bt1, bl[1], br[1], 128, xlbuf, xrbuf);
        gat_fused<4><<<GB, 256, 0, stream>>>(xlbuf, xrbuf, rowptr, csr_src, att[1], bb[1], hbuf, 128, N);
    }
    // ---- layer 2 (H=1, concat=False -> mean over 1 head = identity)
    {
        gemm_mfma<64, true><<<dim3(MB, 1), 256, 0, stream>>>(hbuf, N, Bt2, bl[2], br[2], 32, xlbuf, xrbuf);
        gat_fused<1><<<GB, 256, 0, stream>>>(xlbuf, xrbuf, rowptr, csr_src, att[2], bb[2], hbuf, 32, N);
    }
    // ---- fused global mean pool + head (batch sorted -> binary search, no atomics)
    pool_head_kernel<<<B, 128, 0, stream>>>(hbuf, 32, batch, N, meta, Wh1, bh1, Wh2, bh2, out);
}

// Round 5
// 340.836 us; speedup vs baseline: 1.1947x; 1.0592x over previous
//
#include <hip/hip_runtime.h>
#include <cstdint>
#include <cstddef>

#define NEG_SLOPE 0.2f
#define LOG2E 1.44269504f
#define NBLK 256              // CSR sort: blocks in hist/scatter passes

typedef __attribute__((ext_vector_type(8))) short short8;   // 8 bf16 (4 VGPRs)
typedef __attribute__((ext_vector_type(4))) float f32x4;    // MFMA accumulator

__device__ __forceinline__ float bf2f(unsigned short u) {
    union { unsigned int i; float f; } x; x.i = ((unsigned int)u) << 16; return x.f;
}
__device__ __forceinline__ unsigned short f2bf(float f) {
    union { float f; unsigned int i; } x;
    x.f = f;
    unsigned int u = x.i;
    return (unsigned short)((u + 0x7FFFu + ((u >> 16) & 1u)) >> 16);   // RNE
}

// 8-lane sum via DPP (VALU pipe): xor1, xor2 quad_perms, row_half_mirror.
__device__ __forceinline__ float dpp_sum8(float p) {
    p += __int_as_float(__builtin_amdgcn_update_dpp(0, __float_as_int(p), 0xB1, 0xF, 0xF, true));  // quad_perm [1,0,3,2]
    p += __int_as_float(__builtin_amdgcn_update_dpp(0, __float_as_int(p), 0x4E, 0xF, 0xF, true));  // quad_perm [2,3,0,1]
    p += __int_as_float(__builtin_amdgcn_update_dpp(0, __float_as_int(p), 0x141, 0xF, 0xF, true)); // row_half_mirror
    return p;
}

// =====================================================================
// Weight prep (all 3 layers in one launch):
// Bt[n][k] = bf16([Wl | Wr][k][n]); layer0/1: dout=128, layer2: dout=32.
// =====================================================================
__global__ __launch_bounds__(256) void prep_w_all(
    const float* __restrict__ Wl0, const float* __restrict__ Wr0,
    const float* __restrict__ Wl1, const float* __restrict__ Wr1,
    const float* __restrict__ Wl2, const float* __restrict__ Wr2,
    unsigned short* __restrict__ Bt0, unsigned short* __restrict__ Bt1,
    unsigned short* __restrict__ Bt2)
{
    int idx = blockIdx.x * 256 + threadIdx.x;
    const int SZ = 256 * 128;     // layer0/1 table elems
    const float *Wl, *Wr; unsigned short* Bt; int dout;
    if (idx < SZ)              { Wl = Wl0; Wr = Wr0; Bt = Bt0; dout = 128; }
    else if (idx < 2 * SZ)     { Wl = Wl1; Wr = Wr1; Bt = Bt1; dout = 128; idx -= SZ; }
    else if (idx < 2 * SZ + 64 * 128) { Wl = Wl2; Wr = Wr2; Bt = Bt2; dout = 32; idx -= 2 * SZ; }
    else return;
    int n = idx >> 7, k = idx & 127;
    float v = (n < dout) ? Wl[(size_t)k * dout + n] : Wr[(size_t)k * dout + (n - dout)];
    Bt[idx] = f2bf(v);
}

// =====================================================================
// MFMA GEMM, B-in-LDS / A-direct (r4 winner, frozen).
// Block = 64 rows x BN cols, 256 threads (4 waves).
// =====================================================================
template<int BN, bool ABF16>
__global__ __launch_bounds__(256) void gemm_mfma(
    const void* __restrict__ Avoid, int M,
    const unsigned short* __restrict__ Bt,
    const float* __restrict__ bl, const float* __restrict__ br,
    int dout, unsigned short* __restrict__ XL, unsigned short* __restrict__ XR)
{
    constexpr int LDA = 136;                       // shorts; pad 128+8
    constexpr int NT  = BN / 16;
    __shared__ __attribute__((aligned(16))) unsigned short Bs[BN * LDA];
    const int t  = threadIdx.x;
    const int m0 = blockIdx.x * 64;
    const int n0 = blockIdx.y * BN;

    const int w    = t >> 6;
    const int lane = t & 63;
    const int fr   = lane & 15;
    const int quad = lane >> 4;

    // ---- stage B (BN x 128 bf16 -> LDS), coalesced
#pragma unroll
    for (int i = 0; i < BN / 16; ++i) {
        int c  = t + i * 256;              // short8 chunks
        int n  = c >> 4;                   // 16 chunks per row
        int kc = (c & 15) * 8;
        *(short8*)(Bs + n * LDA + kc) =
            *(const short8*)(Bt + (size_t)(n0 + n) * 128 + kc);
    }

    // ---- load A fragments direct from global (overlaps B staging)
    const int arow = m0 + w * 16 + fr;     // this lane's A row
    const size_t abase = (size_t)(arow < M ? arow : 0) * 128 + quad * 8;
    short8 afr[4];
    if (ABF16) {
        const unsigned short* A = (const unsigned short*)Avoid;
#pragma unroll
        for (int kk = 0; kk < 4; ++kk)
            afr[kk] = *(const short8*)(A + abase + kk * 32);
    } else {
        const float* A = (const float*)Avoid;
#pragma unroll
        for (int kk = 0; kk < 4; ++kk) {
            float4 lo = *(const float4*)(A + abase + kk * 32);
            float4 hi = *(const float4*)(A + abase + kk * 32 + 4);
            afr[kk][0] = (short)f2bf(lo.x); afr[kk][1] = (short)f2bf(lo.y);
            afr[kk][2] = (short)f2bf(lo.z); afr[kk][3] = (short)f2bf(lo.w);
            afr[kk][4] = (short)f2bf(hi.x); afr[kk][5] = (short)f2bf(hi.y);
            afr[kk][6] = (short)f2bf(hi.z); afr[kk][7] = (short)f2bf(hi.w);
        }
    }
    __syncthreads();

    f32x4 acc[NT] = {};
    const unsigned short* bp = Bs + fr * LDA + quad * 8;
#pragma unroll
    for (int kk = 0; kk < 4; ++kk) {
#pragma unroll
        for (int j = 0; j < NT; ++j) {
            short8 bfr = *(const short8*)(bp + j * 16 * LDA + kk * 32);
            acc[j] = __builtin_amdgcn_mfma_f32_16x16x32_bf16(afr[kk], bfr, acc[j], 0, 0, 0);
        }
    }

    // ---- epilogue: +bias, bf16 stores into XL | XR
#pragma unroll
    for (int j = 0; j < NT; ++j) {
        int col = n0 + j * 16 + fr;
        float bias = (col < dout) ? bl[col] : br[col - dout];
#pragma unroll
        for (int r = 0; r < 4; ++r) {
            int row = m0 + w * 16 + quad * 4 + r;
            if (row < M) {
                unsigned short o = f2bf(acc[j][r] + bias);
                if (col < dout) XL[(size_t)row * dout + col] = o;
                else            XR[(size_t)row * dout + (col - dout)] = o;
            }
        }
    }
}

// =====================================================================
// CSR build, ATOMIC-FREE (two-level bucket sort, LDS atomics only).
// Replaces count_rank(800K returning device atomics) + place(scattered
// dependent 2B stores). Edge order within a node's bucket is arbitrary
// (same as the old atomic build).
//   1) csr_hist:   hist[d][b] = #edges of block b with dst>>8 == d
//   2) 3-phase scan over hist (65536, digit-major) -> global offsets
//   3) csr_scatter: packed (dst<<16|src) -> sorted[], coarse-ordered
//   4) csr_fine:   per coarse bucket: fine hist + LDS scan -> rowptr
//                  (incl. rowptr[N]=E) + csr_src scatter
// =====================================================================
__global__ __launch_bounds__(256) void csr_hist(
    const int* __restrict__ dst, int E, int tile, int* __restrict__ hist)
{
    __shared__ int h[256];
    const int t = threadIdx.x, b = blockIdx.x;
    h[t] = 0;
    __syncthreads();
    const int e0 = b * tile;
    const int e1 = min(E, e0 + tile);
    for (int e = e0 + t; e < e1; e += 256)
        atomicAdd(&h[dst[e] >> 8], 1);
    __syncthreads();
    hist[t * NBLK + b] = h[t];
}

__global__ __launch_bounds__(256) void csr_scatter(
    const int* __restrict__ src, const int* __restrict__ dst, int E, int tile,
    const int* __restrict__ hist_s, unsigned int* __restrict__ sorted)
{
    __shared__ int cur[256];
    const int t = threadIdx.x, b = blockIdx.x;
    cur[t] = hist_s[t * NBLK + b];
    __syncthreads();
    const int e0 = b * tile;
    const int e1 = min(E, e0 + tile);
    for (int e = e0 + t; e < e1; e += 256) {
        int d = dst[e];
        int pos = atomicAdd(&cur[d >> 8], 1);
        sorted[pos] = ((unsigned int)d << 16) | (unsigned int)src[e];
    }
}

__global__ __launch_bounds__(256) void csr_fine(
    const unsigned int* __restrict__ sorted, int E, int N,
    const int* __restrict__ hist_s,
    int* __restrict__ rowptr, unsigned short* __restrict__ csr_src)
{
    __shared__ int h[256];
    __shared__ int sc[256];
    const int t = threadIdx.x, d = blockIdx.x;
    const int start = hist_s[d * NBLK];
    const int end   = (d < 255) ? hist_s[(d + 1) * NBLK] : E;
    h[t] = 0;
    __syncthreads();
    for (int e = start + t; e < end; e += 256)
        atomicAdd(&h[(sorted[e] >> 16) & 0xFF], 1);
    __syncthreads();
    int v = h[t];
    sc[t] = v;
    __syncthreads();
    for (int off = 1; off < 256; off <<= 1) {
        int u = (t >= off) ? sc[t - off] : 0;
        __syncthreads();
        sc[t] += u;
        __syncthreads();
    }
    const int base = start + sc[t] - v;    // absolute exclusive prefix
    const int node = (d << 8) + t;
    if (node <= N) rowptr[node] = base;    // node==N lands on E exactly
    h[t] = base;                           // absolute cursor
    __syncthreads();
    for (int e = start + t; e < end; e += 256) {
        unsigned int it = sorted[e];
        int pos = atomicAdd(&h[(it >> 16) & 0xFF], 1);
        csr_src[pos] = (unsigned short)(it & 0xFFFFu);
    }
}

// ---- 3-phase exclusive scan (generic, reused for the 65536 hist) ----
__global__ __launch_bounds__(256) void scan_partial(
    const int* __restrict__ cnt, int N, int* __restrict__ bsum)
{
    __shared__ int red[4];
    const int t = threadIdx.x;
    const int base = blockIdx.x * 2048;
    int s = 0;
#pragma unroll
    for (int i = 0; i < 8; ++i) {
        int idx = base + t + i * 256;
        if (idx < N) s += cnt[idx];
    }
#pragma unroll
    for (int off = 32; off >= 1; off >>= 1) s += __shfl_xor(s, off);
    if ((t & 63) == 0) red[t >> 6] = s;
    __syncthreads();
    if (t == 0) bsum[blockIdx.x] = red[0] + red[1] + red[2] + red[3];
}

__global__ __launch_bounds__(256) void scan_bsums(
    int* __restrict__ bsum, int nb, int E, int* __restrict__ rowptr, int N)
{
    __shared__ int sh[256];
    const int t = threadIdx.x;
    int v = (t < nb) ? bsum[t] : 0;
    sh[t] = v;
    __syncthreads();
    for (int off = 1; off < 256; off <<= 1) {
        int u = (t >= off) ? sh[t - off] : 0;
        __syncthreads();
        sh[t] += u;
        __syncthreads();
    }
    if (t < nb) bsum[t] = sh[t] - v;   // exclusive prefix
    if (t == 0) rowptr[N] = E;
}

__global__ __launch_bounds__(256) void scan_final(
    const int* __restrict__ cnt, int N, const int* __restrict__ bsum,
    int* __restrict__ rowptr)
{
    __shared__ int sdat[2048];
    __shared__ int tsum[256];
    const int t = threadIdx.x;
    const int base = blockIdx.x * 2048;
#pragma unroll
    for (int i = 0; i < 8; ++i) {
        int idx = base + t + i * 256;
        sdat[t + i * 256] = (idx < N) ? cnt[idx] : 0;
    }
    __syncthreads();
    int vals[8];
    int s = 0;
#pragma unroll
    for (int j = 0; j < 8; ++j) { vals[j] = sdat[t * 8 + j]; s += vals[j]; }
    tsum[t] = s;
    __syncthreads();
    for (int off = 1; off < 256; off <<= 1) {
        int u = (t >= off) ? tsum[t - off] : 0;
        __syncthreads();
        tsum[t] += u;
        __syncthreads();
    }
    int run = bsum[blockIdx.x] + tsum[t] - s;   // exclusive prefix of this chunk
#pragma unroll
    for (int j = 0; j < 8; ++j) { sdat[t * 8 + j] = run; run += vals[j]; }
    __syncthreads();
#pragma unroll
    for (int i = 0; i < 8; ++i) {
        int idx = base + t + i * 256;
        if (idx < N) rowptr[idx] = sdat[t + i * 256];
    }
}

// =====================================================================
// Fused GATv2 edge phase (frozen at the gather-fill ceiling ~2.0 TB/s).
// =====================================================================
template<int H>
__global__ __launch_bounds__(256, 4) void gat_fused(
    const unsigned short* __restrict__ xl, const unsigned short* __restrict__ xr,
    const int* __restrict__ rowptr, const unsigned short* __restrict__ csr_src,
    const float* __restrict__ att, const float* __restrict__ bias,
    unsigned short* __restrict__ hout, int hstride, int N)
{
    constexpr int HC  = 32 * H;
    constexpr int LPE = HC / 4;      // lanes per edge (H=4: 32, H=1: 8)
    constexpr int EPW = 64 / LPE;    // edge slots per wave (2 / 8)
    const int node = blockIdx.x * 4 + (threadIdx.x >> 6);
    if (node >= N) return;
    const int lane = threadIdx.x & 63;
    const int q    = lane % LPE;
    const int slot = lane / LPE;
    const int rs   = rowptr[node];
    const int re   = rowptr[node + 1];

    const unsigned short* __restrict__ xlb = xl + 4 * q;
    float4 xri;
    {
        ushort4 u = *(const ushort4*)(xr + (size_t)node * HC + 4 * q);
        xri.x = bf2f(u.x); xri.y = bf2f(u.y); xri.z = bf2f(u.z); xri.w = bf2f(u.w);
    }
    // logit coefs with leaky folded, exp2 domain
    float4 b1, b2;
    {
        float4 a = *(const float4*)(att + 4 * q);
        const float c1 = 0.5f * (1.0f + NEG_SLOPE) * LOG2E;   // 0.6*log2e
        const float c2 = 0.5f * (1.0f - NEG_SLOPE) * LOG2E;   // 0.4*log2e
        b1.x = a.x * c1; b1.y = a.y * c1; b1.z = a.z * c1; b1.w = a.w * c1;
        b2.x = a.x * c2; b2.y = a.y * c2; b2.z = a.z * c2; b2.w = a.w * c2;
    }

    float l = 0.f;
    float4 acc = make_float4(0.f, 0.f, 0.f, 0.f);

    auto ld4 = [&](int s) -> float4 {
        ushort4 u = *(const ushort4*)(xlb + (size_t)s * HC);
        float4 v;
        v.x = bf2f(u.x); v.y = bf2f(u.y); v.z = bf2f(u.z); v.w = bf2f(u.w);
        return v;
    };

    auto edge_w = [&](const float4& v) -> float {   // exp2(att . leakyrelu(v+xri))
        float sx = v.x + xri.x, sy = v.y + xri.y, sz = v.z + xri.z, sw = v.w + xri.w;
        float p  = b1.x * sx;
        float pq = b2.x * fabsf(sx);
        p  = fmaf(b1.y, sy, p);
        pq = fmaf(b2.y, fabsf(sy), pq);
        p  = fmaf(b1.z, sz, p);
        pq = fmaf(b2.z, fabsf(sz), pq);
        p  = fmaf(b1.w, sw, p);
        pq = fmaf(b2.w, fabsf(sw), pq);
        p += pq;
        p = dpp_sum8(p);                 // 8-lane head reduce, VALU pipe
        return exp2f(p);
    };

    // ---- self-loop (src = dst = node), slot 0 only
    if (slot == 0) {
        float4 v = ld4(node);
        float w = edge_w(v);
        l = w;
        acc.x = w * v.x; acc.y = w * v.y; acc.z = w * v.z; acc.w = w * v.w;
    }

    // ---- incoming edges, strided per slot, unrolled x2 (no predication)
    int k = rs + slot;
    for (; k + EPW < re; k += 2 * EPW) {
        int s0 = csr_src[k];
        int s1 = csr_src[k + EPW];
        float4 v0 = ld4(s0);
        float4 v1 = ld4(s1);
        float w0 = edge_w(v0);
        float w1 = edge_w(v1);
        l += w0 + w1;
        acc.x = fmaf(w0, v0.x, fmaf(w1, v1.x, acc.x));
        acc.y = fmaf(w0, v0.y, fmaf(w1, v1.y, acc.y));
        acc.z = fmaf(w0, v0.z, fmaf(w1, v1.z, acc.z));
        acc.w = fmaf(w0, v0.w, fmaf(w1, v1.w, acc.w));
    }
    if (k < re) {
        int s0 = csr_src[k];
        float4 v0 = ld4(s0);
        float w0 = edge_w(v0);
        l += w0;
        acc.x = fmaf(w0, v0.x, acc.x);
        acc.y = fmaf(w0, v0.y, acc.y);
        acc.z = fmaf(w0, v0.z, acc.z);
        acc.w = fmaf(w0, v0.w, acc.w);
    }

    // ---- merge edge slots: plain sums (once per node)
#pragma unroll
    for (int mask = LPE; mask < 64; mask <<= 1) {
        l     += __shfl_xor(l, mask);
        acc.x += __shfl_xor(acc.x, mask);
        acc.y += __shfl_xor(acc.y, mask);
        acc.z += __shfl_xor(acc.z, mask);
        acc.w += __shfl_xor(acc.w, mask);
    }

    if (lane < LPE) {
        const float4 bi = *(const float4*)(bias + 4 * q);
        float inv = 1.f / (l + 1e-16f);
        float4 o;
        o.x = acc.x * inv + bi.x;
        o.y = acc.y * inv + bi.y;
        o.z = acc.z * inv + bi.z;
        o.w = acc.w * inv + bi.w;
        o.x = (o.x > 0.f) ? o.x : expm1f(o.x);
        o.y = (o.y > 0.f) ? o.y : expm1f(o.y);
        o.z = (o.z > 0.f) ? o.z : expm1f(o.z);
        o.w = (o.w > 0.f) ? o.w : expm1f(o.w);
        ushort4 ob;
        ob.x = f2bf(o.x); ob.y = f2bf(o.y); ob.z = f2bf(o.z); ob.w = f2bf(o.w);
        *(ushort4*)(hout + (size_t)node * hstride + 4 * q) = ob;
    }
}

// =====================================================================
// Fused mean-pool + MLP head (h is bf16).
// =====================================================================
__global__ __launch_bounds__(128) void pool_head_kernel(
    const unsigned short* __restrict__ h, int hstride,
    const int* __restrict__ batch, int N,
    const float* __restrict__ meta,
    const float* __restrict__ Wh1, const float* __restrict__ bh1,
    const float* __restrict__ Wh2, const float* __restrict__ bh2,
    float* __restrict__ out)
{
    const int b = blockIdx.x;
    const int t = threadIdx.x;
    __shared__ float s[128];
    __shared__ float z[44];

    int lo = 0, hi = N;
    while (lo < hi) { int mid = (lo + hi) >> 1; if (batch[mid] < b) lo = mid + 1; else hi = mid; }
    int lo2 = lo, hi2 = N;
    while (lo2 < hi2) { int mid = (lo2 + hi2) >> 1; if (batch[mid] < b + 1) lo2 = mid + 1; else hi2 = mid; }
    const int start = lo, end = lo2;

    const int c = t & 31, r = t >> 5;     // 4 rows x 32 channels in flight
    float acc = 0.f;
    for (int row = start + r; row < end; row += 4)
        acc += bf2f(h[(size_t)row * hstride + c]);
    s[t] = acc;
    __syncthreads();
    if (t < 32) {
        float sum = s[t] + s[t + 32] + s[t + 64] + s[t + 96];
        z[t] = sum / fmaxf((float)(end - start), 1.0f);
    } else if (t < 44) {
        z[t] = meta[(size_t)b * 12 + (t - 32)];
    }
    __syncthreads();
    if (t < 32) {
        float hj = bh1[t];
#pragma unroll
        for (int k = 0; k < 44; ++k)
            hj = fmaf(z[k], Wh1[k * 32 + t], hj);
        hj = fmaxf(hj, 0.f);
        float p = hj * Wh2[t];
#pragma unroll
        for (int off = 16; off >= 1; off >>= 1)
            p += __shfl_xor(p, off, 32);
        if (t == 0) out[b] = p + bh2[0];
    }
}

// =====================================================================
extern "C" void kernel_launch(void* const* d_in, const int* in_sizes, int n_in,
                              void* d_out, int out_size, void* d_ws, size_t ws_size,
                              hipStream_t stream)
{
    const float* x     = (const float*)d_in[0];
    const int*   ei    = (const int*)d_in[1];
    const int*   batch = (const int*)d_in[2];
    const float* meta  = (const float*)d_in[3];
    const float* Wl[3]  = {(const float*)d_in[4],  (const float*)d_in[10], (const float*)d_in[16]};
    const float* bl[3]  = {(const float*)d_in[5],  (const float*)d_in[11], (const float*)d_in[17]};
    const float* Wr[3]  = {(const float*)d_in[6],  (const float*)d_in[12], (const float*)d_in[18]};
    const float* br[3]  = {(const float*)d_in[7],  (const float*)d_in[13], (const float*)d_in[19]};
    const float* att[3] = {(const float*)d_in[8],  (const float*)d_in[14], (const float*)d_in[20]};
    const float* bb[3]  = {(const float*)d_in[9],  (const float*)d_in[15], (const float*)d_in[21]};
    const float* Wh1 = (const float*)d_in[22];
    const float* bh1 = (const float*)d_in[23];
    const float* Wh2 = (const float*)d_in[24];
    const float* bh2 = (const float*)d_in[25];
    float* out = (float*)d_out;

    const int N  = in_sizes[0] / 128;
    const int E  = in_sizes[1] / 2;
    const int B  = in_sizes[3] / 12;

    char* wsp = (char*)d_ws;
    size_t off_ = 0;
    auto alloc = [&](size_t bytes) {
        char* p = wsp + off_;
        off_ = (off_ + bytes + 255) & ~(size_t)255;
        return p;
    };
    unsigned short* xlbuf = (unsigned short*)alloc((size_t)N * 128 * 2);  // bf16 gather table
    unsigned short* xrbuf = (unsigned short*)alloc((size_t)N * 128 * 2);  // bf16 xr table
    unsigned short* hbuf  = (unsigned short*)alloc((size_t)N * 128 * 2);  // bf16 layer output
    int*   rowptr  = (int*)alloc((size_t)(N + 1) * 4);
    unsigned short* csr_src = (unsigned short*)alloc((size_t)E * 2);  // src < 65536
    unsigned int*   sorted  = (unsigned int*)alloc((size_t)E * 4);    // (dst<<16)|src, coarse-ordered
    int*   hist_g  = (int*)alloc((size_t)65536 * 4);                  // hist[digit][block]
    int*   hist_s  = (int*)alloc((size_t)65537 * 4);                  // scanned (+ total)
    unsigned short* Bt0     = (unsigned short*)alloc((size_t)256 * 128 * 2);
    unsigned short* Bt1     = (unsigned short*)alloc((size_t)256 * 128 * 2);
    unsigned short* Bt2     = (unsigned short*)alloc((size_t)64 * 128 * 2);
    int*   bsum    = (int*)alloc((size_t)256 * 4);

    const int* srcI = ei;
    const int* dstI = ei + E;

    // ---- weight prep (independent of everything else)
    prep_w_all<<<(2 * 256 * 128 + 64 * 128 + 255) / 256, 256, 0, stream>>>(
        Wl[0], Wr[0], Wl[1], Wr[1], Wl[2], Wr[2], Bt0, Bt1, Bt2);

    // ---- CSR over dst: atomic-free two-level bucket sort
    const int tile = (E + NBLK - 1) / NBLK;
    csr_hist<<<NBLK, 256, 0, stream>>>(dstI, E, tile, hist_g);
    scan_partial<<<32, 256, 0, stream>>>(hist_g, 65536, bsum);
    scan_bsums<<<1, 256, 0, stream>>>(bsum, 32, E, hist_s, 65536);
    scan_final<<<32, 256, 0, stream>>>(hist_g, 65536, bsum, hist_s);
    csr_scatter<<<NBLK, 256, 0, stream>>>(srcI, dstI, E, tile, hist_s, sorted);
    csr_fine<<<(N >> 8) + 1, 256, 0, stream>>>(sorted, E, N, hist_s, rowptr, csr_src);

    const int GB = (N + 3) / 4;     // gat_fused blocks (4 nodes / 256-thread block)
    const int MB = (N + 63) / 64;   // gemm row-tiles (BM=64)

    // ---- layer 0 (din=128 f32, H=4, C=32, concat)
    {
        gemm_mfma<128, false><<<dim3(MB, 2), 256, 0, stream>>>(x, N, Bt0, bl[0], br[0], 128, xlbuf, xrbuf);
        gat_fused<4><<<GB, 256, 0, stream>>>(xlbuf, xrbuf, rowptr, csr_src, att[0], bb[0], hbuf, 128, N);
    }
    // ---- layer 1 (din=128 bf16)
    {
        gemm_mfma<128, true><<<dim3(MB, 2), 256, 0, stream>>>(hbuf, N, Bt1, bl[1], br[1], 128, xlbuf, xrbuf);
        gat_fused<4><<<GB, 256, 0, stream>>>(xlbuf, xrbuf, rowptr, csr_src, att[1], bb[1], hbuf, 128, N);
    }
    // ---- layer 2 (H=1, concat=False -> mean over 1 head = identity)
    {
        gemm_mfma<64, true><<<dim3(MB, 1), 256, 0, stream>>>(hbuf, N, Bt2, bl[2], br[2], 32, xlbuf, xrbuf);
        gat_fused<1><<<GB, 256, 0, stream>>>(xlbuf, xrbuf, rowptr, csr_src, att[2], bb[2], hbuf, 32, N);
    }
    // ---- fused global mean pool + head (batch sorted -> binary search, no atomics)
    pool_head_kernel<<<B, 128, 0, stream>>>(hbuf, 32, batch, N, meta, Wh1, bh1, Wh2, bh2, out);
}